// Round 8
// baseline (219.534 us; speedup 1.0000x reference)
//
#include <hip/hip_runtime.h>
#include <stdint.h>

// ---------------- problem constants ----------------
#define HW_      102400          // 320*320
#define C_       256
#define N_       1024
#define P_       2               // pairs
#define TILES_   1600            // 64-px tiles per src plane
#define CHUNKS_  32              // chunks per (pair, n-block)
#define ITERS_   50              // 50 tiles of 64 px = 3200 px = 10 image rows per chunk
#define NB_      4               // n-blocks of 256 keypoints
#define K2_      144.269504088896340f   // 100 / ln(2)
#define MOFF_    (-72.134752044448170f) // -K2_ * 0.5 (fixed softmax max; cosine logits <= ~1.02)

typedef __attribute__((ext_vector_type(8))) short bf16x8;
typedef __attribute__((ext_vector_type(4))) float f32x4;

// ws layout (bytes):
//   tgt bf16 : [0, 1MB)       2*1024*256 bf16, [p][n][c]
//   partials : [1MB, 3MB)     2*32*2*1024 float4 (S,U,V,-)
//   PN       : [4MB, +100MB)  normalized src bf16 in FRAGMENT-MAJOR layout:
//              per (p,tile): dword index (k*64 + r)*16 + (c-32k)/2  (k = c>>5)
//              -> each wave's (k,h,s) fragment read is ONE contiguous 1KB dwordx4 load
#define WS_TGT_OFF  0
#define WS_PAR_OFF  (1u << 20)
#define WS_PN_OFF   (4u << 20)

__device__ __forceinline__ uint32_t packbf(float a, float b) {
  uint32_t r;
  asm("v_cvt_pk_bf16_f32 %0, %1, %2" : "=v"(r) : "v"(a), "v"(b));
  return r;
}
__device__ __forceinline__ float fexp2(float x) {
  return __builtin_amdgcn_exp2f(x);
}

// ---------------- kernel 1: (a) prenorm dense -> PN (bf16, fragment-major);
// ----------------           (b) tgt normalize -> bf16; copy weights ----------------
__global__ __launch_bounds__(256)
void k_pre(const float* __restrict__ dense, const float* __restrict__ kdesc,
           const float* __restrict__ kscores, uint32_t* __restrict__ PN,
           uint16_t* __restrict__ tgt, float* __restrict__ out) {
  __shared__ float part[16][64];
  __shared__ float sinv[64];
  const int bid = blockIdx.x;
  if (bid < P_ * TILES_) {
    const int p = bid / TILES_, tile = bid % TILES_;
    const int t   = threadIdx.x;
    const int px4 = (t & 15) * 4;          // 4 consecutive px (rows of the tile)
    const int cg  = t >> 4;                // 16 ch-groups of 16 ch
    const float* src = dense + (size_t)(p * 2) * C_ * HW_ + (size_t)(cg * 16) * HW_
                     + tile * 64 + px4;    // src ids 0,2
    // ---- float4 loads (1KB/wave-instr), keep all 64 values in regs ----
    float v[16][4];
    #pragma unroll
    for (int cc = 0; cc < 16; ++cc) {
      const float4 q = *(const float4*)(src + (size_t)cc * HW_);
      v[cc][0] = q.x; v[cc][1] = q.y; v[cc][2] = q.z; v[cc][3] = q.w;
    }
    float ps[4] = {0.f, 0.f, 0.f, 0.f};
    #pragma unroll
    for (int cc = 0; cc < 16; ++cc) {
      #pragma unroll
      for (int i = 0; i < 4; ++i) ps[i] = fmaf(v[cc][i], v[cc][i], ps[i]);
    }
    #pragma unroll
    for (int i = 0; i < 4; ++i) part[cg][px4 + i] = ps[i];
    __syncthreads();
    if (t < 64) {
      float s = 0.f;
      #pragma unroll
      for (int g = 0; g < 16; ++g) s += part[g][t];
      sinv[t] = 1.f / fmaxf(sqrtf(s), 1e-12f);
    }
    __syncthreads();
    // ---- scale + pack + direct fragment-major stores (64B granules completed
    // ---- by lane pairs (l, l+16): halves 0/1 of the same 64B row segment) ----
    uint32_t* dstg = PN + ((size_t)(p * TILES_ + tile) << 13);
    const int kk   = cg >> 1;              // k-slice (32 ch)
    const int half = cg & 1;               // 16-ch half within slice
    #pragma unroll
    for (int i = 0; i < 4; ++i) {
      const int r  = px4 + i;
      const float iv = sinv[r];
      uint32_t* d = dstg + (kk * 64 + r) * 16 + half * 8;
      uint4 A, B;
      A.x = packbf(v[0][i] * iv,  v[1][i] * iv);
      A.y = packbf(v[2][i] * iv,  v[3][i] * iv);
      A.z = packbf(v[4][i] * iv,  v[5][i] * iv);
      A.w = packbf(v[6][i] * iv,  v[7][i] * iv);
      B.x = packbf(v[8][i] * iv,  v[9][i] * iv);
      B.y = packbf(v[10][i] * iv, v[11][i] * iv);
      B.z = packbf(v[12][i] * iv, v[13][i] * iv);
      B.w = packbf(v[14][i] * iv, v[15][i] * iv);
      *(uint4*)&d[0] = A;
      *(uint4*)&d[4] = B;
    }
  } else {
    // ---- tgt keypoint descriptors -> normalized bf16 [p][n][c]; copy weights ----
    const int t = (bid - P_ * TILES_) * 256 + threadIdx.x;   // 0..2047
    const int p = t >> 10, n = t & 1023;
    const float* src = kdesc + (size_t)(p * 2 + 1) * C_ * N_ + n;   // tgt ids 1,3
    float s = 0.f;
    #pragma unroll 16
    for (int c = 0; c < C_; ++c) { const float v2 = src[c * N_]; s = fmaf(v2, v2, s); }
    const float inv = 1.f / fmaxf(sqrtf(s), 1e-12f);
    uint32_t* dst = (uint32_t*)(tgt + (size_t)t * C_);
    #pragma unroll 4
    for (int c8 = 0; c8 < C_; c8 += 8) {
      uint4 wv;
      wv.x = packbf(src[(c8 + 0) * N_] * inv, src[(c8 + 1) * N_] * inv);
      wv.y = packbf(src[(c8 + 2) * N_] * inv, src[(c8 + 3) * N_] * inv);
      wv.z = packbf(src[(c8 + 4) * N_] * inv, src[(c8 + 5) * N_] * inv);
      wv.w = packbf(src[(c8 + 6) * N_] * inv, src[(c8 + 7) * N_] * inv);
      *(uint4*)&dst[c8 / 2] = wv;
    }
    out[4096 + t] = kscores[(p * 2 + 1) * N_ + n];   // match_weights
  }
}

// ---------------- kernel 2: register-direct QK^T + fixed-max softmax + soft-argmax ----------------
// block: 512 thr (8 waves = 2(h) x 4(q)); j=4 -> 64 n/wave, 256 n/block; grid 256 = 1 block/CU.
// NO LDS, NO barriers in the loop: each wave loads its A-fragments straight from PN
// (one coalesced 1KB dwordx4 per fragment) served by L1 (intra-block 4x reuse) and the
// XCD-local L2 (cross-block reuse via co-locating decode; validated FETCH ~110MB).
__global__ __launch_bounds__(512, 2)
void k_main(const uint32_t* __restrict__ PN, const uint16_t* __restrict__ tgt,
            float4* __restrict__ partials) {
  // ---- XCD co-locating decode: same (p,chunk) -> bids {x, x+8, x+16, x+24} ----
  const int bid = blockIdx.x;              // 0..255
  const int xcd = bid & 7;
  const int rr  = bid >> 3;                // 0..31
  const int nb  = rr & 3;
  const int grp = xcd + 8 * (rr >> 2);     // 0..63 = (p, chunk)
  const int p     = grp >> 5;
  const int chunk = grp & 31;

  const int t    = threadIdx.x;
  const int lane = t & 63;
  const int w    = t >> 6;                 // 0..7
  const int l15  = lane & 15;
  const int g4   = lane >> 4;
  const int h    = w & 1;                  // px half (32 rows)
  const int q    = w >> 1;                 // n slice (64 n)

  // ---- B fragments (tgt, [n][c] bf16): 4 j-tiles x 8 k-slices = 128 VGPR ----
  bf16x8 Bf[4][8];
  const int nbase = nb * 256 + q * 64;
  #pragma unroll
  for (int j = 0; j < 4; ++j) {
    const uint16_t* tp = tgt + (size_t)(p * N_ + nbase + j * 16 + l15) * C_ + g4 * 8;
    #pragma unroll
    for (int k = 0; k < 8; ++k) Bf[j][k] = *(const bf16x8*)(tp + k * 32);
  }

  float stS[4], stU[4], stV[4];
  #pragma unroll
  for (int j = 0; j < 4; ++j) { stS[j] = 0.f; stU[j] = 0.f; stV[j] = 0.f; }

  const int lr0 = h * 32 + g4 * 4;         // acc px-row base (s=0)
  // per-lane A-fragment dword offset within a k-slice: row*16 + g4*4
  const int aoff = (h * 32 + l15) * 16 + g4 * 4;

  // static u-offsets within a 64-px tile (tile always inside ONE image row: 320 = 5*64)
  float offf[2][4];
  #pragma unroll
  for (int s = 0; s < 2; ++s)
    #pragma unroll
    for (int e = 0; e < 4; ++e) offf[s][e] = (float)(lr0 + s * 16 + e);

  const uint32_t* PNc = PN + ((size_t)(p * TILES_ + chunk * ITERS_) << 13);

  float u0f = 0.f, v0f = (float)(chunk * 10);
  for (int iter = 0; iter < ITERS_; ++iter) {
    const uint32_t* bt = PNc + ((size_t)iter << 13);

    f32x4 acc[4][2];
    #pragma unroll
    for (int j = 0; j < 4; ++j) {
      acc[j][0] = (f32x4){0.f, 0.f, 0.f, 0.f};
      acc[j][1] = (f32x4){0.f, 0.f, 0.f, 0.f};
    }
    __builtin_amdgcn_s_setprio(1);
    #pragma unroll
    for (int k = 0; k < 8; ++k) {
      const bf16x8 a0 = *(const bf16x8*)&bt[k * 1024 + aoff];         // rows h*32..+15
      const bf16x8 a1 = *(const bf16x8*)&bt[k * 1024 + 256 + aoff];   // rows +16..+31
      acc[0][0] = __builtin_amdgcn_mfma_f32_16x16x32_bf16(a0, Bf[0][k], acc[0][0], 0, 0, 0);
      acc[0][1] = __builtin_amdgcn_mfma_f32_16x16x32_bf16(a1, Bf[0][k], acc[0][1], 0, 0, 0);
      acc[1][0] = __builtin_amdgcn_mfma_f32_16x16x32_bf16(a0, Bf[1][k], acc[1][0], 0, 0, 0);
      acc[1][1] = __builtin_amdgcn_mfma_f32_16x16x32_bf16(a1, Bf[1][k], acc[1][1], 0, 0, 0);
      acc[2][0] = __builtin_amdgcn_mfma_f32_16x16x32_bf16(a0, Bf[2][k], acc[2][0], 0, 0, 0);
      acc[2][1] = __builtin_amdgcn_mfma_f32_16x16x32_bf16(a1, Bf[2][k], acc[2][1], 0, 0, 0);
      acc[3][0] = __builtin_amdgcn_mfma_f32_16x16x32_bf16(a0, Bf[3][k], acc[3][0], 0, 0, 0);
      acc[3][1] = __builtin_amdgcn_mfma_f32_16x16x32_bf16(a1, Bf[3][k], acc[3][1], 0, 0, 0);
    }
    __builtin_amdgcn_s_setprio(0);

    // ---- fixed-max softmax + soft-argmax (v constant per tile; u = u0 + off) ----
    #pragma unroll
    for (int j = 0; j < 4; ++j) {
      float tS = 0.f, tU = 0.f;
      #pragma unroll
      for (int s = 0; s < 2; ++s) {
        #pragma unroll
        for (int e = 0; e < 4; ++e) {
          const float ev = fexp2(fmaf(K2_, acc[j][s][e], MOFF_));
          tS += ev;
          tU = fmaf(ev, offf[s][e], tU);
        }
      }
      stS[j] += tS;
      stU[j] += fmaf(u0f, tS, tU);
      stV[j] = fmaf(v0f, tS, stV[j]);
    }
    u0f += 64.f;
    if (u0f > 290.f) { u0f = 0.f; v0f += 1.f; }   // u0 cycles 0,64,128,192,256
  }

  // ---- merge the 4 g4-groups (disjoint px subsets, same n) ----
  #pragma unroll
  for (int j = 0; j < 4; ++j) {
    float S = stS[j], U = stU[j], V = stV[j];
    S += __shfl_xor(S, 16, 64); U += __shfl_xor(U, 16, 64); V += __shfl_xor(V, 16, 64);
    S += __shfl_xor(S, 32, 64); U += __shfl_xor(U, 32, 64); V += __shfl_xor(V, 32, 64);
    if (lane < 16) {
      const int n = nbase + j * 16 + l15;
      partials[((size_t)(p * CHUNKS_ + chunk) * 2 + h) * N_ + n] = make_float4(S, U, V, 0.f);
    }
  }
}

// ---------------- kernel 3: sum 64 partials per (p, n) -> coords; ids ----------------
__global__ void k_final(const float4* __restrict__ partials, float* __restrict__ out) {
  const int t = blockIdx.x * blockDim.x + threadIdx.x;   // 0..2047
  const int p = t >> 10, n = t & 1023;
  float S = 0.f, U = 0.f, V = 0.f;
  #pragma unroll 4
  for (int s = 0; s < 2 * CHUNKS_; ++s) {
    const float4 v = partials[((size_t)p * 2 * CHUNKS_ + s) * N_ + n];
    S += v.x; U += v.y; V += v.z;
  }
  out[(size_t)(p * N_ + n) * 2 + 0] = U / S;
  out[(size_t)(p * N_ + n) * 2 + 1] = V / S;
  if (t < 4) {
    const float ids[4] = {1.f, 3.f, 0.f, 2.f};  // tgt_ids then src_ids
    out[6144 + t] = ids[t];
  }
}

// ---------------- host launch ----------------
extern "C" void kernel_launch(void* const* d_in, const int* in_sizes, int n_in,
                              void* d_out, int out_size, void* d_ws, size_t ws_size,
                              hipStream_t stream) {
  const float* kscores = (const float*)d_in[0];   // (4,1,1024)
  const float* kdesc   = (const float*)d_in[1];   // (4,256,1024)
  const float* dense   = (const float*)d_in[2];   // (4,256,320,320)
  float* out = (float*)d_out;

  char* ws = (char*)d_ws;
  uint16_t* tgt = (uint16_t*)(ws + WS_TGT_OFF);
  float4*   par = (float4*)(ws + WS_PAR_OFF);
  uint32_t* PN  = (uint32_t*)(ws + WS_PN_OFF);

  k_pre<<<P_ * TILES_ + (P_ * N_) / 256, 256, 0, stream>>>(dense, kdesc, kscores, PN, tgt, out);
  k_main<<<P_ * NB_ * CHUNKS_, 512, 0, stream>>>(PN, tgt, par);
  k_final<<<(P_ * N_) / 256, 256, 0, stream>>>(par, out);
}

// Round 9
// 189.670 us; speedup vs baseline: 1.1575x; 1.1575x over previous
//
#include <hip/hip_runtime.h>
#include <stdint.h>

// ---------------- problem constants ----------------
#define HW_      102400          // 320*320
#define C_       256
#define N_       1024
#define P_       2               // pairs
#define TILES_   1600            // 64-px tiles per src plane
#define CHUNKS_  32              // chunks per (pair, n-block)
#define MEGAS_   25              // 25 mega-iters x 128 px = 3200 px chunk
#define NB_      4               // n-blocks of 256 keypoints
#define K2_      144.269504088896340f   // 100 / ln(2)
#define MOFF_    (-72.134752044448170f) // -K2_ * 0.5 (fixed softmax max; cosine logits <= ~1.02)

typedef __attribute__((ext_vector_type(8)))  short bf16x8;
typedef __attribute__((ext_vector_type(16))) float f32x16;

// ws layout (bytes):
//   tgt bf16 : [0, 1MB)       2*1024*256 bf16, [p][n][c]
//   partials : [1MB, 3MB)     2*32*2*1024 float4 (S,U,V,-)
//   PN       : [4MB, +100MB)  normalized src bf16, 32x32x16-fragment-major:
//              per (p,tile) 8192 dwords: dword = kk*512 + half*256 + r*4 + dd
//              (kk = ch>>4, half = (ch>>3)&1, dd = (ch&7)>>1; r = px row 0..63)
#define WS_TGT_OFF  0
#define WS_PAR_OFF  (1u << 20)
#define WS_PN_OFF   (4u << 20)

__device__ __forceinline__ uint32_t packbf(float a, float b) {
  uint32_t r;
  asm("v_cvt_pk_bf16_f32 %0, %1, %2" : "=v"(r) : "v"(a), "v"(b));
  return r;
}
__device__ __forceinline__ float fexp2(float x) {
  return __builtin_amdgcn_exp2f(x);
}
__device__ __forceinline__ void dma16(const uint32_t* g, uint32_t* l) {
  // async global->LDS, 16B/lane; LDS dest = wave-uniform base + lane*16
  __builtin_amdgcn_global_load_lds(
      (const __attribute__((address_space(1))) uint32_t*)g,
      (__attribute__((address_space(3))) uint32_t*)l, 16, 0, 0);
}

// ---------------- kernel 1: (a) prenorm dense -> PN (bf16, fragment-major);
// ----------------           (b) tgt normalize -> bf16; copy weights ----------------
__global__ __launch_bounds__(256)
void k_pre(const float* __restrict__ dense, const float* __restrict__ kdesc,
           const float* __restrict__ kscores, uint32_t* __restrict__ PN,
           uint16_t* __restrict__ tgt, float* __restrict__ out) {
  __shared__ float part[16][64];
  __shared__ float sinv[64];
  const int bid = blockIdx.x;
  if (bid < P_ * TILES_) {
    const int p = bid / TILES_, tile = bid % TILES_;
    const int t   = threadIdx.x;
    const int px4 = (t & 15) * 4;          // 4 consecutive px rows of the tile
    const int cg  = t >> 4;                // ch-group = k-slice kk (16 ch: cg*16..+15)
    const float* src = dense + (size_t)(p * 2) * C_ * HW_ + (size_t)(cg * 16) * HW_
                     + tile * 64 + px4;    // src ids 0,2
    // ---- float4 loads (1KB/wave-instr), keep all 64 values in regs ----
    float v[16][4];
    #pragma unroll
    for (int cc = 0; cc < 16; ++cc) {
      const float4 qd = *(const float4*)(src + (size_t)cc * HW_);
      v[cc][0] = qd.x; v[cc][1] = qd.y; v[cc][2] = qd.z; v[cc][3] = qd.w;
    }
    float ps[4] = {0.f, 0.f, 0.f, 0.f};
    #pragma unroll
    for (int cc = 0; cc < 16; ++cc) {
      #pragma unroll
      for (int i = 0; i < 4; ++i) ps[i] = fmaf(v[cc][i], v[cc][i], ps[i]);
    }
    #pragma unroll
    for (int i = 0; i < 4; ++i) part[cg][px4 + i] = ps[i];
    __syncthreads();
    if (t < 64) {
      float s = 0.f;
      #pragma unroll
      for (int g = 0; g < 16; ++g) s += part[g][t];
      sinv[t] = 1.f / fmaxf(sqrtf(s), 1e-12f);
    }
    __syncthreads();
    // ---- scale + pack + fragment-major stores (uint4 granules; L2 merges lines) ----
    uint32_t* dstg = PN + ((size_t)(p * TILES_ + tile) << 13) + cg * 512;
    #pragma unroll
    for (int i = 0; i < 4; ++i) {
      const int r  = px4 + i;
      const float iv = sinv[r];
      uint32_t* d = dstg + 4 * r;
      uint4 A, B;
      A.x = packbf(v[0][i] * iv,  v[1][i] * iv);    // ch kk*16+0..7  (half 0)
      A.y = packbf(v[2][i] * iv,  v[3][i] * iv);
      A.z = packbf(v[4][i] * iv,  v[5][i] * iv);
      A.w = packbf(v[6][i] * iv,  v[7][i] * iv);
      B.x = packbf(v[8][i] * iv,  v[9][i] * iv);    // ch kk*16+8..15 (half 1)
      B.y = packbf(v[10][i] * iv, v[11][i] * iv);
      B.z = packbf(v[12][i] * iv, v[13][i] * iv);
      B.w = packbf(v[14][i] * iv, v[15][i] * iv);
      *(uint4*)&d[0]   = A;
      *(uint4*)&d[256] = B;
    }
  } else {
    // ---- tgt keypoint descriptors -> normalized bf16 [p][n][c]; copy weights ----
    const int t = (bid - P_ * TILES_) * 256 + threadIdx.x;   // 0..2047
    const int p = t >> 10, n = t & 1023;
    const float* src = kdesc + (size_t)(p * 2 + 1) * C_ * N_ + n;   // tgt ids 1,3
    float s = 0.f;
    #pragma unroll 16
    for (int c = 0; c < C_; ++c) { const float v2 = src[c * N_]; s = fmaf(v2, v2, s); }
    const float inv = 1.f / fmaxf(sqrtf(s), 1e-12f);
    uint32_t* dst = (uint32_t*)(tgt + (size_t)t * C_);
    #pragma unroll 4
    for (int c8 = 0; c8 < C_; c8 += 8) {
      uint4 wv;
      wv.x = packbf(src[(c8 + 0) * N_] * inv, src[(c8 + 1) * N_] * inv);
      wv.y = packbf(src[(c8 + 2) * N_] * inv, src[(c8 + 3) * N_] * inv);
      wv.z = packbf(src[(c8 + 4) * N_] * inv, src[(c8 + 5) * N_] * inv);
      wv.w = packbf(src[(c8 + 6) * N_] * inv, src[(c8 + 7) * N_] * inv);
      *(uint4*)&dst[c8 / 2] = wv;
    }
    out[4096 + t] = kscores[(p * 2 + 1) * N_ + n];   // match_weights
  }
}

// ---------------- kernel 2: 32x32x16 MFMA + fixed-max softmax + soft-argmax ----------------
// block: 512 thr (8 waves = 2(h) x 4(q)); 64 n/wave (j=2), 256 n/block; grid 256 = 1 block/CU.
// Mega-iter = 128 px (2 subtiles), double-buffered 2x64KB LDS, ONE barrier per mega.
// Per mega: 64 dma16 + 256 ds_read_b128 + 512 MFMA(32x32) + softmax; 4 indep MFMA chains.
// The 4 blocks sharing a (p,chunk) map to the SAME XCD (validated: FETCH ~110MB).
__global__ __launch_bounds__(512, 2)
void k_main(const uint32_t* __restrict__ PN, const uint16_t* __restrict__ tgt,
            float4* __restrict__ partials) {
  __shared__ uint32_t lds[2 * 16384];   // 2 bufs x 64 KB (two 32KB tiles each) = 128 KB

  // ---- XCD co-locating decode: same (p,chunk) -> bids {x, x+8, x+16, x+24} ----
  const int bid = blockIdx.x;              // 0..255
  const int xcd = bid & 7;
  const int rr  = bid >> 3;                // 0..31
  const int nb  = rr & 3;
  const int grp = xcd + 8 * (rr >> 2);     // 0..63 = (p, chunk)
  const int p     = grp >> 5;
  const int chunk = grp & 31;

  const int t    = threadIdx.x;
  const int lane = t & 63;
  const int w    = t >> 6;                 // 0..7
  const int l31  = lane & 31;
  const int hi   = lane >> 5;
  const int h    = w & 1;                  // px half (32 rows)
  const int q    = w >> 1;                 // n slice (64 n)

  // ---- B fragments (tgt): Bf[j][kk] lane holds B[k=kk*16+hi*8+e][n=nbase+j*32+l31] ----
  bf16x8 Bf[2][16];                        // 128 VGPR
  const int nbase = nb * 256 + q * 64;
  #pragma unroll
  for (int j = 0; j < 2; ++j) {
    const uint16_t* tp = tgt + (size_t)(p * N_ + nbase + j * 32 + l31) * C_ + hi * 8;
    #pragma unroll
    for (int kk = 0; kk < 16; ++kk) Bf[j][kk] = *(const bf16x8*)(tp + kk * 16);
  }

  float stS[2], stU[2], stV[2];
  #pragma unroll
  for (int j = 0; j < 2; ++j) { stS[j] = 0.f; stU[j] = 0.f; stV[j] = 0.f; }

  // A-frag dword offset within a k-slice block: half(=hi)*256 + row*4
  const int arow = hi * 256 + (h * 32 + l31) * 4;
  const float ubstat = (float)(h * 32 + 4 * hi);   // static part of u-base

  // DMA: wave w stages dwords w*2048..+2047 of the 16384-dword mega (8 dma16)
  const uint32_t* PNc = PN + ((size_t)(p * TILES_ + chunk * 2 * MEGAS_) << 13) + w * 2048 + lane * 4;
  uint32_t* ldsw = &lds[w * 2048];

  // ---- prologue: stage mega 0 into buf 0 ----
  #pragma unroll
  for (int jj = 0; jj < 8; ++jj) dma16(PNc + jj * 256, ldsw + jj * 256);
  __syncthreads();

  float u0f = 0.f, v0f = (float)(chunk * 10);
  for (int m = 0; m < MEGAS_; ++m) {
    // ---- issue next mega's DMA into the other buffer ----
    if (m + 1 < MEGAS_) {
      const uint32_t* s = PNc + ((size_t)(m + 1) << 14);
      uint32_t* d = ldsw + (((m + 1) & 1) ? 16384 : 0);
      #pragma unroll
      for (int jj = 0; jj < 8; ++jj) dma16(s + jj * 256, d + jj * 256);
    }

    // ---- MFMA: 2 subtiles x 2 j = 4 independent 16-deep chains ----
    const uint32_t* buf = &lds[(m & 1) * 16384];
    f32x16 acc[2][2];                      // [sub][j], 64 VGPR
    #pragma unroll
    for (int s2 = 0; s2 < 2; ++s2)
      #pragma unroll
      for (int j = 0; j < 2; ++j)
        #pragma unroll
        for (int e = 0; e < 16; ++e) acc[s2][j][e] = 0.f;

    __builtin_amdgcn_s_setprio(1);
    #pragma unroll
    for (int kk = 0; kk < 16; ++kk) {
      const bf16x8 a0 = *(const bf16x8*)&buf[kk * 512 + arow];          // subtile 0
      const bf16x8 a1 = *(const bf16x8*)&buf[8192 + kk * 512 + arow];   // subtile 1
      acc[0][0] = __builtin_amdgcn_mfma_f32_32x32x16_bf16(a0, Bf[0][kk], acc[0][0], 0, 0, 0);
      acc[0][1] = __builtin_amdgcn_mfma_f32_32x32x16_bf16(a0, Bf[1][kk], acc[0][1], 0, 0, 0);
      acc[1][0] = __builtin_amdgcn_mfma_f32_32x32x16_bf16(a1, Bf[0][kk], acc[1][0], 0, 0, 0);
      acc[1][1] = __builtin_amdgcn_mfma_f32_32x32x16_bf16(a1, Bf[1][kk], acc[1][1], 0, 0, 0);
    }
    __builtin_amdgcn_s_setprio(0);

    // ---- fixed-max softmax + soft-argmax; C/D row = (r&3)+8*(r>>2)+4*hi (+h*32) ----
    #pragma unroll
    for (int s2 = 0; s2 < 2; ++s2) {
      const float ub = u0f + ubstat;       // u of this lane's row r=0 element
      #pragma unroll
      for (int j = 0; j < 2; ++j) {
        float tS = 0.f, tC = 0.f;
        #pragma unroll
        for (int r = 0; r < 16; ++r) {
          const float ev = fexp2(fmaf(K2_, acc[s2][j][r], MOFF_));
          tS += ev;
          tC = fmaf(ev, (float)((r & 3) + 8 * (r >> 2)), tC);
        }
        stS[j] += tS;
        stU[j] = fmaf(ub, tS, stU[j] + tC);
        stV[j] = fmaf(v0f, tS, stV[j]);
      }
      u0f += 64.f;
      if (u0f > 290.f) { u0f = 0.f; v0f += 1.f; }   // u0 cycles 0,64,128,192,256
    }

    __syncthreads();   // drains next-mega DMAs (issued ~4000 cy ago) + publishes
  }

  // ---- merge hi halves (disjoint px rows, same n) ----
  #pragma unroll
  for (int j = 0; j < 2; ++j) {
    float S = stS[j], U = stU[j], V = stV[j];
    S += __shfl_xor(S, 32, 64); U += __shfl_xor(U, 32, 64); V += __shfl_xor(V, 32, 64);
    if (lane < 32) {
      const int n = nbase + j * 32 + l31;
      partials[((size_t)(p * CHUNKS_ + chunk) * 2 + h) * N_ + n] = make_float4(S, U, V, 0.f);
    }
  }
}

// ---------------- kernel 3: sum 64 partials per (p, n) -> coords; ids ----------------
__global__ void k_final(const float4* __restrict__ partials, float* __restrict__ out) {
  const int t = blockIdx.x * blockDim.x + threadIdx.x;   // 0..2047
  const int p = t >> 10, n = t & 1023;
  float S = 0.f, U = 0.f, V = 0.f;
  #pragma unroll 4
  for (int s = 0; s < 2 * CHUNKS_; ++s) {
    const float4 v = partials[((size_t)p * 2 * CHUNKS_ + s) * N_ + n];
    S += v.x; U += v.y; V += v.z;
  }
  out[(size_t)(p * N_ + n) * 2 + 0] = U / S;
  out[(size_t)(p * N_ + n) * 2 + 1] = V / S;
  if (t < 4) {
    const float ids[4] = {1.f, 3.f, 0.f, 2.f};  // tgt_ids then src_ids
    out[6144 + t] = ids[t];
  }
}

// ---------------- host launch ----------------
extern "C" void kernel_launch(void* const* d_in, const int* in_sizes, int n_in,
                              void* d_out, int out_size, void* d_ws, size_t ws_size,
                              hipStream_t stream) {
  const float* kscores = (const float*)d_in[0];   // (4,1,1024)
  const float* kdesc   = (const float*)d_in[1];   // (4,256,1024)
  const float* dense   = (const float*)d_in[2];   // (4,256,320,320)
  float* out = (float*)d_out;

  char* ws = (char*)d_ws;
  uint16_t* tgt = (uint16_t*)(ws + WS_TGT_OFF);
  float4*   par = (float4*)(ws + WS_PAR_OFF);
  uint32_t* PN  = (uint32_t*)(ws + WS_PN_OFF);

  k_pre<<<P_ * TILES_ + (P_ * N_) / 256, 256, 0, stream>>>(dense, kdesc, kscores, PN, tgt, out);
  k_main<<<P_ * NB_ * CHUNKS_, 512, 0, stream>>>(PN, tgt, par);
  k_final<<<(P_ * N_) / 256, 256, 0, stream>>>(par, out);
}